// Round 5
// baseline (38412.875 us; speedup 1.0000x reference)
//
#include <hip/hip_runtime.h>

typedef unsigned short u16;
typedef unsigned int u32;
typedef unsigned long long u64;

typedef __bf16 bf16x8 __attribute__((ext_vector_type(8)));
typedef float f32x4 __attribute__((ext_vector_type(4)));
typedef u16 u16x4 __attribute__((ext_vector_type(4)));
typedef u32 u32x2 __attribute__((ext_vector_type(2)));
typedef u32 u32x4 __attribute__((ext_vector_type(4)));

#define T_DIM 8192
#define H_DIM 1024
#define IN_DIM 2048
#define FOURH 4096
#define NWG 256                       // recurrence WGs; 4 hidden units each (1 wave/unit)
#define XW_BYTES ((u64)T_DIM * FOURH * 2)

__device__ __forceinline__ float bf2f(u16 v) { return __uint_as_float(((u32)v) << 16); }
__device__ __forceinline__ float bf2f_hi(u32 v) { return __uint_as_float(v & 0xffff0000u); }
__device__ __forceinline__ float bf2f_lo(u32 v) { return __uint_as_float(v << 16); }
__device__ __forceinline__ u16 f2bf(float f) {
  u32 x = __float_as_uint(f);
  return (u16)((x + 0x7fffu + ((x >> 16) & 1u)) >> 16);  // RNE
}
__device__ __forceinline__ float sigm(float x) { return 1.f / (1.f + __expf(-x)); }
__device__ __forceinline__ float tanh_f(float x) { return 1.f - 2.f / (__expf(2.f * x) + 1.f); }

// ---------------------------------------------------------------------------
// Phase 1: xW[T,4H] = x[T,IN] @ W_ih[4H,IN]^T + (b_ih + b_hh).
// fp32 inputs converted to bf16 during LDS staging; bf16 MFMA, fp32 acc,
// bf16 xW out. Epilogue remaps columns: newcol = unit*4 + g
// (col = g*1024 + unit), so one unit's 4 gate values are 8 contiguous bytes.
// ---------------------------------------------------------------------------
__global__ __launch_bounds__(256) void gemm_xw(
    const float* __restrict__ A, const float* __restrict__ B,
    const float* __restrict__ b_ih, const float* __restrict__ b_hh,
    u16* __restrict__ C) {
  __shared__ u16 As[128 * 32];
  __shared__ u16 Bs[128 * 32];
  const int tid = threadIdx.x;
  const int bm = blockIdx.y * 128;
  const int bn = blockIdx.x * 128;
  const int wave = tid >> 6, lane = tid & 63;
  const int wm = (wave >> 1) * 64, wn = (wave & 1) * 64;
  const int quad = lane >> 4, l15 = lane & 15;
  f32x4 acc[4][4];
#pragma unroll
  for (int i = 0; i < 4; ++i)
#pragma unroll
    for (int j = 0; j < 4; ++j) acc[i][j] = (f32x4)(0.f);

  const int r0 = tid >> 3;        // 0..31, 4 rows per thread (stride 32)
  const int kc0 = (tid & 7) * 4;  // 4-float chunk within the 32-wide k-tile

  for (int k0 = 0; k0 < IN_DIM; k0 += 32) {
    __syncthreads();
#pragma unroll
    for (int i = 0; i < 4; ++i) {
      const int row = r0 + i * 32;
      const f32x4 av = *(const f32x4*)(A + (u64)(bm + row) * IN_DIM + k0 + kc0);
      const f32x4 bv = *(const f32x4*)(B + (u64)(bn + row) * IN_DIM + k0 + kc0);
      u16x4 ap, bp;
#pragma unroll
      for (int e = 0; e < 4; ++e) { ap[e] = f2bf(av[e]); bp[e] = f2bf(bv[e]); }
      *(u16x4*)&As[row * 32 + kc0] = ap;
      *(u16x4*)&Bs[row * 32 + kc0] = bp;
    }
    __syncthreads();
    bf16x8 af[4], bfr[4];
#pragma unroll
    for (int mi = 0; mi < 4; ++mi)
      af[mi] = *(const bf16x8*)&As[(wm + mi * 16 + l15) * 32 + quad * 8];
#pragma unroll
    for (int ni = 0; ni < 4; ++ni)
      bfr[ni] = *(const bf16x8*)&Bs[(wn + ni * 16 + l15) * 32 + quad * 8];
#pragma unroll
    for (int mi = 0; mi < 4; ++mi)
#pragma unroll
      for (int ni = 0; ni < 4; ++ni)
        acc[mi][ni] = __builtin_amdgcn_mfma_f32_16x16x32_bf16(af[mi], bfr[ni], acc[mi][ni], 0, 0, 0);
  }
  // epilogue: C/D layout col=lane&15, row=quad*4+reg (m89/m91-verified)
#pragma unroll
  for (int ni = 0; ni < 4; ++ni) {
    const int col = bn + wn + ni * 16 + l15;            // col = g*1024 + unit
    const float bias = b_ih[col] + b_hh[col];
    const int newcol = (col & 1023) * 4 + (col >> 10);  // unit*4 + g
#pragma unroll
    for (int mi = 0; mi < 4; ++mi) {
#pragma unroll
      for (int r = 0; r < 4; ++r) {
        const int row = bm + wm + mi * 16 + quad * 4 + r;
        C[(u64)row * FOURH + newcol] = f2bf(acc[mi][ni][r] + bias);
      }
    }
  }
}

// ---------------------------------------------------------------------------
// Phase 2: sequential LSTM. 256 persistent WGs x 256 threads (1/CU).
// WG wg owns units [4wg, 4wg+4); wave w owns unit 4wg+w (64-lane k-reduce).
// W_hh slice (16 rows x 1024) staged ONCE in LDS as bf16 (32 KB); per step
// each lane hoists its 64 weights into 32 packed u32 VGPRs via ds_read -
// lgkmcnt is independent of the poll's vmcnt, so this is free latency-wise,
// and 32 regs of payload cannot trigger the R4 spill.
// h exchanged as u32 words: (bf16(h)<<16) | tag16, 1024 words per parity
// buffer at the MALL. Consumer polls 2 u64 relaxed agent atomic loads
// (4 units/thread); h staged into parity-double-buffered LDS.
// ---------------------------------------------------------------------------
__global__ __launch_bounds__(256, 1) void lstm_rec(
    const u16* __restrict__ xw2, const float* __restrict__ W_hh, u32* hbuf) {
  __shared__ u16 Wl[16][1024];     // [g*4 + w][k] bf16 weights, 32 KB
  __shared__ float h_s[2][1024];   // parity-double-buffered h
  const int tid = threadIdx.x;
  const int wg = blockIdx.x;
  const int w = tid >> 6;          // wave = unit slot
  const int lane = tid & 63;
  const int unit = wg * 4 + w;

  // --- stage W_hh -> bf16 LDS (once). thread: row tid>>4, cols (tid&15)*64..
  {
    const int r = tid >> 4;                  // 0..15 = g*4 + uw
    const int g = r >> 2, uw = r & 3;
    const int c0 = (tid & 15) * 64;
    const float* src = W_hh + (u64)(g * H_DIM + wg * 4 + uw) * H_DIM + c0;
#pragma unroll
    for (int cc = 0; cc < 64; cc += 8) {
      const f32x4 a = *(const f32x4*)(src + cc);
      const f32x4 b = *(const f32x4*)(src + cc + 4);
      u32x4 pk;
      pk[0] = ((u32)f2bf(a[1]) << 16) | (u32)f2bf(a[0]);
      pk[1] = ((u32)f2bf(a[3]) << 16) | (u32)f2bf(a[2]);
      pk[2] = ((u32)f2bf(b[1]) << 16) | (u32)f2bf(b[0]);
      pk[3] = ((u32)f2bf(b[3]) << 16) | (u32)f2bf(b[2]);
      *(u32x4*)&Wl[r][c0 + cc] = pk;
    }
  }
  __syncthreads();

  float c = 0.f;      // cell state (lane 0 of each wave)
  float xwv[4];       // current-step xw gate values (lane 0)
  if (lane == 0) {
    const u32* xp = (const u32*)(xw2 + (u64)0 * FOURH + unit * 4);
    const u32 x0 = xp[0], x1 = xp[1];
    xwv[0] = bf2f_lo(x0); xwv[1] = bf2f_hi(x0);
    xwv[2] = bf2f_lo(x1); xwv[3] = bf2f_hi(x1);
  }

  for (int t = 0; t < T_DIM; ++t) {
    const int par = t & 1;
    // (a) hoist weights LDS->regs BEFORE the poll: lgkmcnt, hidden under sync.
    //     lane reads k in {4*lane + 256*v}, v<4: bank stride 2*lane -> 4-way.
    u32x2 wr[16];
#pragma unroll
    for (int g = 0; g < 4; ++g)
#pragma unroll
      for (int v = 0; v < 4; ++v)
        wr[g * 4 + v] = *(const u32x2*)&Wl[g * 4 + w][4 * lane + 256 * v];

    // (b) poll: 2 u64 relaxed agent atomic loads covering units 4tid..4tid+3
    if (t > 0) {
      const u64* hb = (const u64*)(hbuf + (u64)par * H_DIM) + tid * 2;
      const u32 want = (u32)t & 0xffffu;
      u64 v0, v1;
      for (;;) {
        v0 = __hip_atomic_load(hb + 0, __ATOMIC_RELAXED, __HIP_MEMORY_SCOPE_AGENT);
        v1 = __hip_atomic_load(hb + 1, __ATOMIC_RELAXED, __HIP_MEMORY_SCOPE_AGENT);
        const u32 bad = (((u32)v0 & 0xffffu) ^ want) | (((u32)(v0 >> 32) & 0xffffu) ^ want) |
                        (((u32)v1 & 0xffffu) ^ want) | (((u32)(v1 >> 32) & 0xffffu) ^ want);
        if (bad == 0u) break;
        __builtin_amdgcn_s_sleep(1);
      }
      f32x4 hv;
      hv[0] = bf2f_hi((u32)v0); hv[1] = bf2f_hi((u32)(v0 >> 32));
      hv[2] = bf2f_hi((u32)v1); hv[3] = bf2f_hi((u32)(v1 >> 32));
      *(f32x4*)&h_s[par][tid * 4] = hv;
    } else {
      *(f32x4*)&h_s[0][tid * 4] = (f32x4)(0.f);
    }
    // (c) xw prefetch for t+1 AFTER detect: its vmcnt never gates the poll
    float xwn[4];
    if (lane == 0) {
      const int tn = (t + 1 < T_DIM) ? (t + 1) : t;
      const u32* xp = (const u32*)(xw2 + (u64)tn * FOURH + unit * 4);
      const u32 x0 = xp[0], x1 = xp[1];
      xwn[0] = bf2f_lo(x0); xwn[1] = bf2f_hi(x0);
      xwn[2] = bf2f_lo(x1); xwn[3] = bf2f_hi(x1);
    }
    __syncthreads();

    // (d) MAC: 4 gates x 16 k per lane; weights already in regs.
    float a0 = 0.f, a1 = 0.f, a2 = 0.f, a3 = 0.f;
#pragma unroll
    for (int v = 0; v < 4; ++v) {
      const f32x4 hv = *(const f32x4*)&h_s[par][4 * lane + 256 * v];
      const u32x2 w0 = wr[0 * 4 + v], w1 = wr[1 * 4 + v];
      const u32x2 w2 = wr[2 * 4 + v], w3 = wr[3 * 4 + v];
      a0 = __builtin_fmaf(bf2f_lo(w0[0]), hv[0], a0);
      a0 = __builtin_fmaf(bf2f_hi(w0[0]), hv[1], a0);
      a0 = __builtin_fmaf(bf2f_lo(w0[1]), hv[2], a0);
      a0 = __builtin_fmaf(bf2f_hi(w0[1]), hv[3], a0);
      a1 = __builtin_fmaf(bf2f_lo(w1[0]), hv[0], a1);
      a1 = __builtin_fmaf(bf2f_hi(w1[0]), hv[1], a1);
      a1 = __builtin_fmaf(bf2f_lo(w1[1]), hv[2], a1);
      a1 = __builtin_fmaf(bf2f_hi(w1[1]), hv[3], a1);
      a2 = __builtin_fmaf(bf2f_lo(w2[0]), hv[0], a2);
      a2 = __builtin_fmaf(bf2f_hi(w2[0]), hv[1], a2);
      a2 = __builtin_fmaf(bf2f_lo(w2[1]), hv[2], a2);
      a2 = __builtin_fmaf(bf2f_hi(w2[1]), hv[3], a2);
      a3 = __builtin_fmaf(bf2f_lo(w3[0]), hv[0], a3);
      a3 = __builtin_fmaf(bf2f_hi(w3[0]), hv[1], a3);
      a3 = __builtin_fmaf(bf2f_lo(w3[1]), hv[2], a3);
      a3 = __builtin_fmaf(bf2f_hi(w3[1]), hv[3], a3);
    }
    // (e) reduce across the full 64-lane wave
#pragma unroll
    for (int off = 32; off > 0; off >>= 1) {
      a0 += __shfl_down(a0, off);
      a1 += __shfl_down(a1, off);
      a2 += __shfl_down(a2, off);
      a3 += __shfl_down(a3, off);
    }
    // (f) gates + publish (lane 0; one u32 agent store per unit)
    if (lane == 0) {
      const float iv = sigm(a0 + xwv[0]);
      const float fv = sigm(a1 + xwv[1]);
      const float gv = tanh_f(a2 + xwv[2]);
      const float ov = sigm(a3 + xwv[3]);
      c = fv * c + iv * gv;
      const float h = ov * tanh_f(c);
      const u32 pk = ((u32)f2bf(h) << 16) | ((u32)(t + 1) & 0xffffu);
      __hip_atomic_store(hbuf + (u64)((t + 1) & 1) * H_DIM + unit, pk,
                         __ATOMIC_RELAXED, __HIP_MEMORY_SCOPE_AGENT);
      xwv[0] = xwn[0]; xwv[1] = xwn[1]; xwv[2] = xwn[2]; xwv[3] = xwn[3];
    }
    // Second barrier unneeded: h_s is parity-double-buffered, and the WG's
    // per-step __syncthreads bounds wave skew to <1 step (all-to-all consume).
  }
}

// ---------------------------------------------------------------------------
// Phase 3: out = sigmoid(relu(h_T @ W1^T + b1) @ W2^T + b2). One block, fp32.
// h_T lives in hbuf[0..1024) (T even): word u = (bf16(h_u)<<16) | tag.
// ---------------------------------------------------------------------------
__global__ __launch_bounds__(256) void classifier(
    const u32* __restrict__ hb, const float* __restrict__ W1, const float* __restrict__ b1,
    const float* __restrict__ W2, const float* __restrict__ b2, float* __restrict__ out) {
  __shared__ float h_s[1024];
  __shared__ float hid_s[128];
  const int tid = threadIdx.x;
#pragma unroll
  for (int i = 0; i < 4; ++i) {
    const int k = tid + i * 256;
    h_s[k] = bf2f((u16)(hb[k] >> 16));
  }
  __syncthreads();
  const int row = tid >> 1, sb = tid & 1;   // 2 threads per MID row
  const float* wr = W1 + (u64)row * H_DIM + sb * 512;
  float a = 0.f;
  for (int kk = 0; kk < 512; kk += 4) {
    const f32x4 ch = *(const f32x4*)(wr + kk);
#pragma unroll
    for (int e = 0; e < 4; ++e) a = __builtin_fmaf(ch[e], h_s[sb * 512 + kk + e], a);
  }
  a += __shfl_down(a, 1, 2);
  if (sb == 0) hid_s[row] = fmaxf(a + b1[row], 0.f);
  __syncthreads();
  if (tid < 64) {
    float p = hid_s[tid] * W2[tid] + hid_s[tid + 64] * W2[tid + 64];
#pragma unroll
    for (int off = 32; off > 0; off >>= 1) p += __shfl_down(p, off, 64);
    if (tid == 0) out[0] = sigm(p + b2[0]);
  }
}

extern "C" void kernel_launch(void* const* d_in, const int* in_sizes, int n_in,
                              void* d_out, int out_size, void* d_ws, size_t ws_size,
                              hipStream_t stream) {
  const float* x_seq = (const float*)d_in[0];
  const float* W_ih  = (const float*)d_in[1];
  const float* W_hh  = (const float*)d_in[2];
  const float* b_ih  = (const float*)d_in[3];
  const float* b_hh  = (const float*)d_in[4];
  const float* W1    = (const float*)d_in[5];
  const float* b1    = (const float*)d_in[6];
  const float* W2    = (const float*)d_in[7];
  const float* b2    = (const float*)d_in[8];

  u16* xW   = (u16*)d_ws;                         // 64 MB bf16 [T, 4H] (unit*4+g layout)
  u32* hbuf = (u32*)((char*)d_ws + XW_BYTES);     // 2 x 1024 x 4B (bf16|tag16)

  gemm_xw<<<dim3(FOURH / 128, T_DIM / 128), 256, 0, stream>>>(x_seq, W_ih, b_ih, b_hh, xW);
  lstm_rec<<<NWG, 256, 0, stream>>>(xW, W_hh, hbuf);
  classifier<<<1, 256, 0, stream>>>(hbuf, W1, b1, W2, b2, (float*)d_out);
}